// Round 11
// baseline (3624.647 us; speedup 1.0000x reference)
//
#include <hip/hip_runtime.h>
#include <math.h>

#define EPS 1e-12f

// ---------------------------------------------------------------------------
// Kernel A: L2-normalize key rows (4096 x 64) into workspace.
// ---------------------------------------------------------------------------
__global__ __launch_bounds__(256)
void nkeys_kernel(const float* __restrict__ keys, float* __restrict__ kn)
{
    const int m = blockIdx.x * 256 + threadIdx.x;   // 0..4095
    const float4* src = reinterpret_cast<const float4*>(keys + (size_t)m * 64);
    float4 v[16];
    float s0 = 0.f, s1 = 0.f, s2 = 0.f, s3 = 0.f;
#pragma unroll
    for (int i = 0; i < 16; ++i) {
        v[i] = src[i];
        s0 = fmaf(v[i].x, v[i].x, s0);
        s1 = fmaf(v[i].y, v[i].y, s1);
        s2 = fmaf(v[i].z, v[i].z, s2);
        s3 = fmaf(v[i].w, v[i].w, s3);
    }
    const float n = sqrtf((s0 + s1) + (s2 + s3));
    const float d = fmaxf(n, EPS);
    float4* dst = reinterpret_cast<float4*>(kn + (size_t)m * 64);
#pragma unroll
    for (int i = 0; i < 16; ++i) {
        float4 o;
        o.x = v[i].x / d; o.y = v[i].y / d; o.z = v[i].z / d; o.w = v[i].w / d;
        dst[i] = o;
    }
}

// ---- quad-lane (team) butterfly adds via DPP quad_perm: pure VALU ----
__device__ __forceinline__ float qp_xor1(float v) {
    return __int_as_float(__builtin_amdgcn_update_dpp(
        0, __float_as_int(v), 0xB1 /*quad_perm [1,0,3,2]*/, 0xF, 0xF, true));
}
__device__ __forceinline__ float qp_xor2(float v) {
    return __int_as_float(__builtin_amdgcn_update_dpp(
        0, __float_as_int(v), 0x4E /*quad_perm [2,3,0,1]*/, 0xF, 0xF, true));
}

// ---------------------------------------------------------------------------
// Kernel B, restructured for a <=80-VGPR working set (round-6/9 evidence: the
// allocator pins this kernel at 80 VGPRs regardless of __launch_bounds__, so
// the 152-reg rows-in-lanes layout spilled qreg to scratch -> 2022us).
//
// New layout: 4-lane TEAM per query row. team = lane>>2 picks the row,
// sub = lane&3 owns channels [16*sub, 16*sub+16).
// Per lane: qreg[16] + 4xfloat4 key quarter + pks[8] u64 ~= 65 VGPR.
// Dot product: 16 FMAs/lane + 2 DPP-butterfly adds -> full sim on all 4
// team lanes (bit-identical: IEEE add is commutative, so the predicate is
// team-uniform and the redundant pks lists stay identical). Each wave owns
// 16 rows, scans ALL 4096 keys; no LDS, no __syncthreads, no merge.
// ---------------------------------------------------------------------------
__global__ __launch_bounds__(256, 2)
void kvmem_kernel(const float* __restrict__ q,       // [16][64][4096]
                  const float* __restrict__ kn,      // [4096][64] normalized
                  const float* __restrict__ values,  // [4096][64] raw
                  float* __restrict__ out)           // [16][64][4096]
{
    const int lane = threadIdx.x & 63;
    const int sub  = lane & 3;                        // channel quarter
    const int team = lane >> 2;                       // 0..15: row within wave
    const int wid  = (blockIdx.x << 2) + (threadIdx.x >> 6);  // 0..4095
    const int row  = (wid << 4) + team;               // global query row
    const int b    = row >> 12;                       // batch
    const int hw   = row & 4095;                      // spatial index

    // ---- load own 16 channels of the q row ----
    const float* qb = q + (size_t)b * 262144 + hw;
    float qreg[16];
#pragma unroll
    for (int i = 0; i < 16; ++i)
        qreg[i] = qb[(size_t)(sub * 16 + i) * 4096];

    // ---- normalize: team butterfly for the 64-c sum of squares ----
    {
        float s0 = 0.f, s1 = 0.f, s2 = 0.f, s3 = 0.f;
#pragma unroll
        for (int i = 0; i < 16; i += 4) {
            s0 = fmaf(qreg[i + 0], qreg[i + 0], s0);
            s1 = fmaf(qreg[i + 1], qreg[i + 1], s1);
            s2 = fmaf(qreg[i + 2], qreg[i + 2], s2);
            s3 = fmaf(qreg[i + 3], qreg[i + 3], s3);
        }
        float ss = (s0 + s1) + (s2 + s3);
        ss += qp_xor1(ss);
        ss += qp_xor2(ss);                            // all 4 lanes: full sum
        const float d = fmaxf(sqrtf(ss), EPS);
#pragma unroll
        for (int i = 0; i < 16; ++i) qreg[i] = qreg[i] / d;   // IEEE div
    }

    // ---- top-8 state: packed u64 = sortable(sim)<<12 | (4095-idx) ----
    // desc order == (sim desc, idx asc) == jax.lax.top_k tie rule.
    unsigned long long pks[8];
#pragma unroll
    for (int j = 0; j < 8; ++j) pks[j] = 0x7FFFFFull << 12;   // ~ -inf
    float thr = -INFINITY;

    const float4* kbase = reinterpret_cast<const float4*>(kn) + sub * 4;

    for (int m = 0; m < 4096; ++m) {
        const float4* kc = kbase + (size_t)m * 16;    // lane's quarter of key m
        const float4 k0 = kc[0];
        const float4 k1 = kc[1];
        const float4 k2 = kc[2];
        const float4 k3 = kc[3];

        float a0 = 0.f, a1 = 0.f, a2 = 0.f, a3 = 0.f;
        a0 = fmaf(qreg[ 0], k0.x, a0); a1 = fmaf(qreg[ 1], k0.y, a1);
        a2 = fmaf(qreg[ 2], k0.z, a2); a3 = fmaf(qreg[ 3], k0.w, a3);
        a0 = fmaf(qreg[ 4], k1.x, a0); a1 = fmaf(qreg[ 5], k1.y, a1);
        a2 = fmaf(qreg[ 6], k1.z, a2); a3 = fmaf(qreg[ 7], k1.w, a3);
        a0 = fmaf(qreg[ 8], k2.x, a0); a1 = fmaf(qreg[ 9], k2.y, a1);
        a2 = fmaf(qreg[10], k2.z, a2); a3 = fmaf(qreg[11], k2.w, a3);
        a0 = fmaf(qreg[12], k3.x, a0); a1 = fmaf(qreg[13], k3.y, a1);
        a2 = fmaf(qreg[14], k3.z, a2); a3 = fmaf(qreg[15], k3.w, a3);

        float s = (a0 + a1) + (a2 + a3);              // lane partial (16 c)
        s += qp_xor1(s);
        s += qp_xor2(s);                              // full sim on all 4 lanes

        if (s > thr) {                                // team-uniform predicate
            unsigned int su = __float_as_uint(s);
            su ^= (unsigned int)((int)su >> 31) | 0x80000000u;
            unsigned long long cv =
                ((unsigned long long)su << 12) |
                (unsigned long long)(4095 - m);
#pragma unroll
            for (int j = 0; j < 8; ++j) {             // branchless bubble
                const unsigned long long o = pks[j];
                const bool sw = cv > o;
                pks[j] = sw ? cv : o;
                cv     = sw ? o  : cv;
            }
            const unsigned int u7 = (unsigned int)(pks[7] >> 12);
            const unsigned int s7 =
                (u7 & 0x80000000u) ? (u7 ^ 0x80000000u) : ~u7;
            thr = __uint_as_float(s7);
        }
    }

    // ---- unpack exact top-8 sims + indices (identical on team lanes) ----
    float wv[8];
    int   id[8];
#pragma unroll
    for (int j = 0; j < 8; ++j) {
        const unsigned int u  = (unsigned int)(pks[j] >> 12);
        const unsigned int su = (u & 0x80000000u) ? (u ^ 0x80000000u) : ~u;
        wv[j] = __uint_as_float(su);
        id[j] = 4095 - (int)((unsigned int)pks[j] & 0xFFFu);
    }

    // ---- softmax over 8 (wv[0] is max: sorted desc) ----
    const float mx = wv[0];
    float e[8];
    float esum = 0.f;
#pragma unroll
    for (int j = 0; j < 8; ++j) { e[j] = expf(wv[j] - mx); esum += e[j]; }
#pragma unroll
    for (int j = 0; j < 8; ++j) e[j] = e[j] / esum;

    // ---- weighted gather: lane accumulates its 16 channels ----
    float acc[16];
#pragma unroll
    for (int i = 0; i < 16; ++i) acc[i] = 0.f;
#pragma unroll
    for (int j = 0; j < 8; ++j) {
        const float4* vr =
            reinterpret_cast<const float4*>(values + (size_t)id[j] * 64) + sub * 4;
        const float wj = e[j];
#pragma unroll
        for (int i = 0; i < 4; ++i) {
            const float4 v = vr[i];
            acc[4 * i + 0] = fmaf(wj, v.x, acc[4 * i + 0]);
            acc[4 * i + 1] = fmaf(wj, v.y, acc[4 * i + 1]);
            acc[4 * i + 2] = fmaf(wj, v.z, acc[4 * i + 2]);
            acc[4 * i + 3] = fmaf(wj, v.w, acc[4 * i + 3]);
        }
    }

    // ---- store lane's 16 channels of its row ----
    float* ob = out + (size_t)b * 262144 + hw;
#pragma unroll
    for (int i = 0; i < 16; ++i)
        ob[(size_t)(sub * 16 + i) * 4096] = acc[i];
}

// ---------------------------------------------------------------------------
extern "C" void kernel_launch(void* const* d_in, const int* in_sizes, int n_in,
                              void* d_out, int out_size, void* d_ws, size_t ws_size,
                              hipStream_t stream)
{
    const float* q      = (const float*)d_in[0];   // [16][64][64][64]
    const float* keys   = (const float*)d_in[1];   // [4096][64]
    const float* values = (const float*)d_in[2];   // [4096][64]
    float*       out    = (float*)d_out;           // [16][64][64][64]
    float*       kn     = (float*)d_ws;            // 4096*64 floats = 1 MB

    nkeys_kernel<<<16, 256, 0, stream>>>(keys, kn);
    kvmem_kernel<<<1024, 256, 0, stream>>>(q, kn, values, out);
}

// Round 14
// 626.417 us; speedup vs baseline: 5.7863x; 5.7863x over previous
//
#include <hip/hip_runtime.h>
#include <math.h>

#define EPS 1e-12f

typedef float f32x4 __attribute__((ext_vector_type(4)));
typedef short bf16x8 __attribute__((ext_vector_type(8)));

// round-to-nearest-even fp32 -> bf16 (bits)
__device__ __forceinline__ unsigned short f2bf(float x) {
    unsigned int u = __float_as_uint(x);
    unsigned int r = u + 0x7FFFu + ((u >> 16) & 1u);
    return (unsigned short)(r >> 16);
}

// ---- quad-lane butterfly adds via DPP quad_perm (validated round 11) ----
__device__ __forceinline__ float qp_xor1(float v) {
    return __int_as_float(__builtin_amdgcn_update_dpp(
        0, __float_as_int(v), 0xB1, 0xF, 0xF, true));
}
__device__ __forceinline__ float qp_xor2(float v) {
    return __int_as_float(__builtin_amdgcn_update_dpp(
        0, __float_as_int(v), 0x4E, 0xF, 0xF, true));
}

// ---------------------------------------------------------------------------
// Stage 1: normalize keys; emit fp32 kn + bf16 hi/lo split for MFMA.
// ---------------------------------------------------------------------------
__global__ __launch_bounds__(256)
void nkeys_kernel(const float* __restrict__ keys, float* __restrict__ kn,
                  unsigned short* __restrict__ kh, unsigned short* __restrict__ kl)
{
    const int m = blockIdx.x * 256 + threadIdx.x;   // 0..4095
    const float4* src = reinterpret_cast<const float4*>(keys + (size_t)m * 64);
    float4 v[16];
    float s0 = 0.f, s1 = 0.f, s2 = 0.f, s3 = 0.f;
#pragma unroll
    for (int i = 0; i < 16; ++i) {
        v[i] = src[i];
        s0 = fmaf(v[i].x, v[i].x, s0);
        s1 = fmaf(v[i].y, v[i].y, s1);
        s2 = fmaf(v[i].z, v[i].z, s2);
        s3 = fmaf(v[i].w, v[i].w, s3);
    }
    const float d = fmaxf(sqrtf((s0 + s1) + (s2 + s3)), EPS);
    float4* dst = reinterpret_cast<float4*>(kn + (size_t)m * 64);
#pragma unroll
    for (int i = 0; i < 16; ++i) {
        float4 o;
        o.x = v[i].x / d; o.y = v[i].y / d; o.z = v[i].z / d; o.w = v[i].w / d;
        dst[i] = o;
        // bf16 hi/lo split of the 4 normalized channels
        float ch[4] = {o.x, o.y, o.z, o.w};
        unsigned int hw0, hw1, lw0, lw1;
        {
            unsigned short h0 = f2bf(ch[0]), h1 = f2bf(ch[1]);
            unsigned short h2 = f2bf(ch[2]), h3 = f2bf(ch[3]);
            hw0 = (unsigned)h0 | ((unsigned)h1 << 16);
            hw1 = (unsigned)h2 | ((unsigned)h3 << 16);
            unsigned short l0 = f2bf(ch[0] - __uint_as_float((unsigned)h0 << 16));
            unsigned short l1 = f2bf(ch[1] - __uint_as_float((unsigned)h1 << 16));
            unsigned short l2 = f2bf(ch[2] - __uint_as_float((unsigned)h2 << 16));
            unsigned short l3 = f2bf(ch[3] - __uint_as_float((unsigned)h3 << 16));
            lw0 = (unsigned)l0 | ((unsigned)l1 << 16);
            lw1 = (unsigned)l2 | ((unsigned)l3 << 16);
        }
        *reinterpret_cast<uint2*>(kh + (size_t)m * 64 + i * 4) = make_uint2(hw0, hw1);
        *reinterpret_cast<uint2*>(kl + (size_t)m * 64 + i * 4) = make_uint2(lw0, lw1);
    }
}

// ---------------------------------------------------------------------------
// Stage 2: MFMA sim (bf16x3 split, unnormalized q: ranking-invariant) +
// in-register per-lane top-8 -> 32 candidate indices per row.
// Wave: 16 q-rows. Keys-as-A (row = lane&15 = key-in-tile), q-as-B
// (col = lane&15 = q-row). D: col = lane&15, row = (lane>>4)*4 + reg (m89).
// Each lane keeps top-8 over its disjoint key stripe (lane>>4)*4+{0..3} mod 16.
// k-index mapping assumed IDENTICAL for A and B fragments (symmetric 16x16
// design): any shared bijection preserves the dot product.
// ---------------------------------------------------------------------------
__global__ __launch_bounds__(256)
void sim_topk_kernel(const float* __restrict__ q,
                     const unsigned short* __restrict__ kh,
                     const unsigned short* __restrict__ kl,
                     unsigned short* __restrict__ cands)
{
    const int lane = threadIdx.x & 63;
    const int qcol = lane & 15;                       // q-row within tile; also A key row
    const int kgrp = lane >> 4;                       // 0..3
    const int wid  = (blockIdx.x << 2) + (threadIdx.x >> 6);   // 0..4095
    const int row  = (wid << 4) + qcol;               // global q row
    const int b    = row >> 12;
    const int hw   = row & 4095;

    // ---- B fragments: q hi/lo, channels (K) = 32h + kgrp*8 + j ----
    bf16x8 bhi0, bhi1, blo0, blo1;
    {
        const float* qp = q + (size_t)b * 262144 + hw;
#pragma unroll
        for (int j = 0; j < 8; ++j) {
            const float x0 = qp[(size_t)(kgrp * 8 + j) * 4096];
            const unsigned short h0 = f2bf(x0);
            bhi0[j] = (short)h0;
            blo0[j] = (short)f2bf(x0 - __uint_as_float((unsigned)h0 << 16));
            const float x1 = qp[(size_t)(32 + kgrp * 8 + j) * 4096];
            const unsigned short h1 = f2bf(x1);
            bhi1[j] = (short)h1;
            blo1[j] = (short)f2bf(x1 - __uint_as_float((unsigned)h1 << 16));
        }
    }

    // ---- running top-8 (packed u64 = sortable(sim)<<12 | (4095-idx)) ----
    unsigned long long pks[8];
#pragma unroll
    for (int j = 0; j < 8; ++j) pks[j] = 0x7FFFFFull << 12;
    float thr = -INFINITY;

    const size_t off0 = (size_t)qcol * 64 + kgrp * 8; // ushort offset in key tile

    for (int t = 0; t < 256; ++t) {
        const unsigned short* ph = kh + off0 + (size_t)t * 1024;
        const unsigned short* pl = kl + off0 + (size_t)t * 1024;
        const bf16x8 ah0 = *reinterpret_cast<const bf16x8*>(ph);
        const bf16x8 ah1 = *reinterpret_cast<const bf16x8*>(ph + 32);
        const bf16x8 al0 = *reinterpret_cast<const bf16x8*>(pl);
        const bf16x8 al1 = *reinterpret_cast<const bf16x8*>(pl + 32);

        f32x4 d0 = {0.f, 0.f, 0.f, 0.f};
        f32x4 d1 = {0.f, 0.f, 0.f, 0.f};
        f32x4 d2 = {0.f, 0.f, 0.f, 0.f};
        d0 = __builtin_amdgcn_mfma_f32_16x16x32_bf16(ah0, bhi0, d0, 0, 0, 0);
        d1 = __builtin_amdgcn_mfma_f32_16x16x32_bf16(ah0, blo0, d1, 0, 0, 0);
        d2 = __builtin_amdgcn_mfma_f32_16x16x32_bf16(al0, bhi0, d2, 0, 0, 0);
        d0 = __builtin_amdgcn_mfma_f32_16x16x32_bf16(ah1, bhi1, d0, 0, 0, 0);
        d1 = __builtin_amdgcn_mfma_f32_16x16x32_bf16(ah1, blo1, d1, 0, 0, 0);
        d2 = __builtin_amdgcn_mfma_f32_16x16x32_bf16(al1, bhi1, d2, 0, 0, 0);

        float s[4];
#pragma unroll
        for (int j = 0; j < 4; ++j) s[j] = (d0[j] + d1[j]) + d2[j];

        const float smax = fmaxf(fmaxf(s[0], s[1]), fmaxf(s[2], s[3]));
        if (smax > thr) {
#pragma unroll
            for (int j = 0; j < 4; ++j) {
                if (s[j] > thr) {
                    unsigned int su = __float_as_uint(s[j]);
                    su ^= (unsigned int)((int)su >> 31) | 0x80000000u;
                    const int key = (t << 4) + kgrp * 4 + j;
                    unsigned long long cv =
                        ((unsigned long long)su << 12) |
                        (unsigned long long)(4095 - key);
#pragma unroll
                    for (int k = 0; k < 8; ++k) {
                        const unsigned long long o = pks[k];
                        const bool sw = cv > o;
                        pks[k] = sw ? cv : o;
                        cv     = sw ? o  : cv;
                    }
                    const unsigned int u7 = (unsigned int)(pks[7] >> 12);
                    const unsigned int s7 =
                        (u7 & 0x80000000u) ? (u7 ^ 0x80000000u) : ~u7;
                    thr = __uint_as_float(s7);
                }
            }
        }
    }

    // ---- emit 8 candidate indices (u16), 32 per row across the 4 kgrps ----
    unsigned int w[4];
#pragma unroll
    for (int p = 0; p < 4; ++p) {
        const unsigned int i0 = 4095u - (unsigned int)(pks[2 * p]     & 0xFFFu);
        const unsigned int i1 = 4095u - (unsigned int)(pks[2 * p + 1] & 0xFFFu);
        w[p] = i0 | (i1 << 16);
    }
    *reinterpret_cast<uint4*>(cands + (size_t)row * 32 + kgrp * 8) =
        make_uint4(w[0], w[1], w[2], w[3]);
}

// ---------------------------------------------------------------------------
// Stage 3: exact fp32 rescore of the 32 candidates, top-8, softmax, gather.
// Team-of-4 structure validated in round 11 (team-uniform bitwise sims).
// ---------------------------------------------------------------------------
__global__ __launch_bounds__(256)
void finalize_kernel(const float* __restrict__ q,
                     const float* __restrict__ kn,
                     const float* __restrict__ values,
                     const unsigned short* __restrict__ cands,
                     float* __restrict__ out)
{
    const int lane = threadIdx.x & 63;
    const int sub  = lane & 3;
    const int team = lane >> 2;
    const int wid  = (blockIdx.x << 2) + (threadIdx.x >> 6);
    const int row  = (wid << 4) + team;
    const int b    = row >> 12;
    const int hw   = row & 4095;

    // ---- load own 16 channels of q row; team-normalize (exact, eps) ----
    const float* qb = q + (size_t)b * 262144 + hw;
    float qreg[16];
#pragma unroll
    for (int i = 0; i < 16; ++i)
        qreg[i] = qb[(size_t)(sub * 16 + i) * 4096];
    {
        float s0 = 0.f, s1 = 0.f, s2 = 0.f, s3 = 0.f;
#pragma unroll
        for (int i = 0; i < 16; i += 4) {
            s0 = fmaf(qreg[i + 0], qreg[i + 0], s0);
            s1 = fmaf(qreg[i + 1], qreg[i + 1], s1);
            s2 = fmaf(qreg[i + 2], qreg[i + 2], s2);
            s3 = fmaf(qreg[i + 3], qreg[i + 3], s3);
        }
        float ss = (s0 + s1) + (s2 + s3);
        ss += qp_xor1(ss);
        ss += qp_xor2(ss);
        const float d = fmaxf(sqrtf(ss), EPS);
#pragma unroll
        for (int i = 0; i < 16; ++i) qreg[i] = qreg[i] / d;
    }

    // ---- candidate indices (32 u16) ----
    const uint4* cp = reinterpret_cast<const uint4*>(cands + (size_t)row * 32);
    const uint4 c0 = cp[0], c1 = cp[1], c2 = cp[2], c3 = cp[3];
    const unsigned int wds[16] = {c0.x, c0.y, c0.z, c0.w,
                                  c1.x, c1.y, c1.z, c1.w,
                                  c2.x, c2.y, c2.z, c2.w,
                                  c3.x, c3.y, c3.z, c3.w};

    unsigned long long pks[8];
#pragma unroll
    for (int j = 0; j < 8; ++j) pks[j] = 0x7FFFFFull << 12;
    float thr = -INFINITY;

#pragma unroll
    for (int c = 0; c < 32; ++c) {
        const int m = (int)((wds[c >> 1] >> ((c & 1) * 16)) & 0xFFFFu);
        const float4* kc =
            reinterpret_cast<const float4*>(kn + (size_t)m * 64) + sub * 4;
        const float4 k0 = kc[0], k1 = kc[1], k2 = kc[2], k3 = kc[3];
        float a0 = 0.f, a1 = 0.f, a2 = 0.f, a3 = 0.f;
        a0 = fmaf(qreg[ 0], k0.x, a0); a1 = fmaf(qreg[ 1], k0.y, a1);
        a2 = fmaf(qreg[ 2], k0.z, a2); a3 = fmaf(qreg[ 3], k0.w, a3);
        a0 = fmaf(qreg[ 4], k1.x, a0); a1 = fmaf(qreg[ 5], k1.y, a1);
        a2 = fmaf(qreg[ 6], k1.z, a2); a3 = fmaf(qreg[ 7], k1.w, a3);
        a0 = fmaf(qreg[ 8], k2.x, a0); a1 = fmaf(qreg[ 9], k2.y, a1);
        a2 = fmaf(qreg[10], k2.z, a2); a3 = fmaf(qreg[11], k2.w, a3);
        a0 = fmaf(qreg[12], k3.x, a0); a1 = fmaf(qreg[13], k3.y, a1);
        a2 = fmaf(qreg[14], k3.z, a2); a3 = fmaf(qreg[15], k3.w, a3);
        float s = (a0 + a1) + (a2 + a3);
        s += qp_xor1(s);
        s += qp_xor2(s);                       // exact sim, team-uniform

        if (s > thr) {
            unsigned int su = __float_as_uint(s);
            su ^= (unsigned int)((int)su >> 31) | 0x80000000u;
            unsigned long long cv =
                ((unsigned long long)su << 12) | (unsigned long long)(4095 - m);
#pragma unroll
            for (int k = 0; k < 8; ++k) {
                const unsigned long long o = pks[k];
                const bool sw = cv > o;
                pks[k] = sw ? cv : o;
                cv     = sw ? o  : cv;
            }
            const unsigned int u7 = (unsigned int)(pks[7] >> 12);
            const unsigned int s7 =
                (u7 & 0x80000000u) ? (u7 ^ 0x80000000u) : ~u7;
            thr = __uint_as_float(s7);
        }
    }

    // ---- unpack, softmax, weighted gather, store (round-11 validated) ----
    float wv[8];
    int   id[8];
#pragma unroll
    for (int j = 0; j < 8; ++j) {
        const unsigned int u  = (unsigned int)(pks[j] >> 12);
        const unsigned int su = (u & 0x80000000u) ? (u ^ 0x80000000u) : ~u;
        wv[j] = __uint_as_float(su);
        id[j] = 4095 - (int)((unsigned int)pks[j] & 0xFFFu);
    }
    const float mx = wv[0];
    float e[8];
    float esum = 0.f;
#pragma unroll
    for (int j = 0; j < 8; ++j) { e[j] = expf(wv[j] - mx); esum += e[j]; }
#pragma unroll
    for (int j = 0; j < 8; ++j) e[j] = e[j] / esum;

    float acc[16];
#pragma unroll
    for (int i = 0; i < 16; ++i) acc[i] = 0.f;
#pragma unroll
    for (int j = 0; j < 8; ++j) {
        const float4* vr =
            reinterpret_cast<const float4*>(values + (size_t)id[j] * 64) + sub * 4;
        const float wj = e[j];
#pragma unroll
        for (int i = 0; i < 4; ++i) {
            const float4 v = vr[i];
            acc[4 * i + 0] = fmaf(wj, v.x, acc[4 * i + 0]);
            acc[4 * i + 1] = fmaf(wj, v.y, acc[4 * i + 1]);
            acc[4 * i + 2] = fmaf(wj, v.z, acc[4 * i + 2]);
            acc[4 * i + 3] = fmaf(wj, v.w, acc[4 * i + 3]);
        }
    }
    float* ob = out + (size_t)b * 262144 + hw;
#pragma unroll
    for (int i = 0; i < 16; ++i)
        ob[(size_t)(sub * 16 + i) * 4096] = acc[i];
}

// ---------------------------------------------------------------------------
extern "C" void kernel_launch(void* const* d_in, const int* in_sizes, int n_in,
                              void* d_out, int out_size, void* d_ws, size_t ws_size,
                              hipStream_t stream)
{
    const float* q      = (const float*)d_in[0];   // [16][64][64][64]
    const float* keys   = (const float*)d_in[1];   // [4096][64]
    const float* values = (const float*)d_in[2];   // [4096][64]
    float*       out    = (float*)d_out;           // [16][64][64][64]

    char* w = (char*)d_ws;                         // needs 6 MB total
    float*          kn    = (float*)w;                          // 1 MB
    unsigned short* kh    = (unsigned short*)(w + (1u << 20));  // 512 KB
    unsigned short* kl    = (unsigned short*)(w + 1536u * 1024);// 512 KB
    unsigned short* cands = (unsigned short*)(w + (2u << 20));  // 4 MB

    nkeys_kernel<<<16, 256, 0, stream>>>(keys, kn, kh, kl);
    sim_topk_kernel<<<1024, 256, 0, stream>>>(q, kh, kl, cands);
    finalize_kernel<<<1024, 256, 0, stream>>>(q, kn, values, cands, out);
}